// Round 8
// baseline (128.378 us; speedup 1.0000x reference)
//
#include <hip/hip_runtime.h>
#include <math.h>

// Problem constants
#define T_DIM 8192
#define N_DIM 4096
#define L 64
#define P 32
#define IN_DIM 192
#define S_CHUNK 16
#define N_CHUNK (T_DIM / S_CHUNK)   // 512
#define LDST 68                     // padded LDS row stride (float4-aligned)

using f32x4   = __attribute__((ext_vector_type(4))) float;
using bf16x8  = __attribute__((ext_vector_type(8))) short;
using ushort8 = __attribute__((ext_vector_type(8))) unsigned short;

__device__ __forceinline__ unsigned short f2bf(float x) {
  unsigned u = __float_as_uint(x);
  u += 0x7fffu + ((u >> 16) & 1u);           // round-to-nearest-even
  return (unsigned short)(u >> 16);
}
__device__ __forceinline__ float bf2f(unsigned short h) {
  return __uint_as_float(((unsigned)h) << 16);
}

// Packed fragment layout (both X and U):
//   pk[tile16][g][lane] = 8 bf16 of row (tile16*16 + lane), k-chunk g
//   g in 0..15: g<8 -> hi bits of k=8g..8g+7 ; g>=8 -> lo residual of k=8(g-8)..
// A wave's fragment load (lane l = lg*16+lr, k-base gb) is the contiguous
// 1 KiB block at ((tile16*16+gb)*16)*8 + l*8 -> one coalesced dwordx4.
__device__ __forceinline__ bf16x8 ldfrag(const unsigned short* __restrict__ base,
                                         int tile16, int gb, int lg, int lr) {
  return *(const bf16x8*)(base + ((size_t)((tile16 * 16 + gb + lg) * 16 + lr)) * 8);
}

// ---------------- kernel A: partial sums for xh0 = U^T x0; also zeroes acc ----------------
__global__ __launch_bounds__(64) void k_xh0_part(const float* __restrict__ U,
                                                 const float* __restrict__ Xtr,
                                                 float* __restrict__ part,
                                                 double* __restrict__ acc) {
  int b = blockIdx.x;
  int l = threadIdx.x;
  if (b == 0 && l < 2) acc[l] = 0.0;           // replaces hipMemsetAsync
  int n0 = b * 64;
  float s = 0.f;
  #pragma unroll 8
  for (int i = 0; i < 64; ++i) {
    float x = Xtr[n0 + i];
    s += U[(size_t)(n0 + i) * L + l] * x;
  }
  part[b * 64 + l] = s;
}

// ---------------- kernel A2: split U into bf16 hi/lo, PACKED fragment layout ----------------
__global__ __launch_bounds__(256) void k_usplit(const float* __restrict__ U,
                                                unsigned short* __restrict__ upk) {
  int idx = blockIdx.x * 256 + threadIdx.x;   // 0 .. N/16*256-1
  int lr = idx & 15, g = (idx >> 4) & 15, nn16 = idx >> 8;
  int n = nn16 * 16 + lr;
  int k0 = (g & 7) * 8;
  float4 a = *(const float4*)(U + (size_t)n * L + k0);
  float4 b = *(const float4*)(U + (size_t)n * L + k0 + 4);
  ushort8 o;
  float v[8] = {a.x, a.y, a.z, a.w, b.x, b.y, b.z, b.w};
  #pragma unroll
  for (int j = 0; j < 8; ++j) {
    unsigned short h = f2bf(v[j]);
    o[j] = (g < 8) ? h : f2bf(v[j] - bf2f(h));
  }
  *(ushort8*)(upk + (size_t)idx * 8) = o;     // idx == (nn16*16+g)*16+lr
}

// ---------------- kernel B: argmax, temp, build M, xh0, matrix doublings ----------------
__global__ __launch_bounds__(256, 1) void k_prep(const float* __restrict__ A_tilde,
                                                 const float* __restrict__ phi_bar_t,
                                                 const float* __restrict__ logits,
                                                 const float* __restrict__ temp,
                                                 const float* __restrict__ part,
                                                 float* __restrict__ Wm,
                                                 float* __restrict__ xh0,
                                                 float* __restrict__ out_tail) {
  __shared__ float buf[2][64 * LDST];   // 34816 B
  __shared__ float sphi[P * L];         // 8192 B
  __shared__ float spart[4 * 64];       // 1024 B
  __shared__ int   sel_s[P];
  int tid = threadIdx.x;

  // ---- phase 1a: A_tilde -> buf[0] (float4, coalesced) ----
  #pragma unroll
  for (int i = 0; i < 4; ++i) {
    int f = tid + 256 * i;              // f4 index 0..1023
    int r = f >> 4, q = f & 15;
    float4 v = ((const float4*)A_tilde)[f];
    *(float4*)(buf[0] + r * LDST + q * 4) = v;
  }
  // ---- phase 1b: phi -> sphi (float4) ----
  #pragma unroll
  for (int i = 0; i < 2; ++i) {
    int f = tid + 256 * i;              // 0..511
    ((float4*)sphi)[f] = ((const float4*)phi_bar_t)[f];
  }
  // ---- phase 1c: part partial-reduce (coalesced, 4-way parallel over q) ----
  {
    int l = tid & 63, q = tid >> 6;
    float s = 0.f;
    #pragma unroll
    for (int i = 0; i < 16; ++i)
      s += part[(q * 16 + i) * 64 + l];
    spart[q * 64 + l] = s;
  }
  // ---- phase 1d: argmax per logits row; 8-lane groups, float4 reads ----
  {
    int p = tid >> 3, d = tid & 7;      // row, lane-in-group
    const float* row = logits + p * IN_DIM;
    float best = -1e30f; int bk = 0;
    #pragma unroll
    for (int j = 0; j < 6; ++j) {
      int kb = (j * 8 + d) * 4;
      float4 v = *(const float4*)(row + kb);
      if (v.x > best) { best = v.x; bk = kb; }
      if (v.y > best) { best = v.y; bk = kb + 1; }
      if (v.z > best) { best = v.z; bk = kb + 2; }
      if (v.w > best) { best = v.w; bk = kb + 3; }
    }
    #pragma unroll
    for (int off = 4; off > 0; off >>= 1) {
      float vo = __shfl_down(best, off, 8);
      int   ko = __shfl_down(bk,   off, 8);
      if (vo > best || (vo == best && ko < bk)) { best = vo; bk = ko; }
    }
    if (d == 0) {
      sel_s[p] = bk;
      out_tail[2 + p] = (float)bk;
    }
  }
  if (tid == 255) out_tail[1] = fmaxf(0.01f, temp[0] * 0.999f);
  __syncthreads();

  // ---- phase 2: scatter phi into M rows; finish xh0 ----
  if (tid < L) {
    #pragma unroll 4
    for (int p = 0; p < P; ++p) {
      int kk = sel_s[p]; if (kk > L - 1) kk = L - 1;
      buf[0][tid * LDST + kk] += sphi[p * L + tid];
    }
  } else if (tid < 128) {
    int l = tid - 64;
    xh0[l] = spart[l] + spart[64 + l] + spart[128 + l] + spart[192 + l];
  }
  __syncthreads();

  // ---- phase 3: W_0 = M out; 12 squarings with 4x4 register blocking ----
  #pragma unroll
  for (int i = 0; i < 4; ++i) {
    int f = tid + 256 * i;
    int r = f >> 4, q = f & 15;
    *(float4*)(Wm + r * 64 + q * 4) = *(const float4*)(buf[0] + r * LDST + q * 4);
  }

  int r0 = (tid >> 4) << 2;   // 0..60
  int c0 = (tid & 15) << 2;   // 0..60
  int cur = 0;
  for (int j = 1; j <= 12; ++j) {
    const float* S = buf[cur];
    float* D = buf[cur ^ 1];
    float acc[4][4];
    #pragma unroll
    for (int i = 0; i < 4; ++i)
      #pragma unroll
      for (int c = 0; c < 4; ++c) acc[i][c] = 0.f;

    #pragma unroll
    for (int kb = 0; kb < 64; kb += 16) {
      float a[4][16];
      #pragma unroll
      for (int i = 0; i < 4; ++i)
        #pragma unroll
        for (int q = 0; q < 4; ++q) {
          float4 t4 = *(const float4*)(S + (r0 + i) * LDST + kb + q * 4);
          a[i][q * 4 + 0] = t4.x; a[i][q * 4 + 1] = t4.y;
          a[i][q * 4 + 2] = t4.z; a[i][q * 4 + 3] = t4.w;
        }
      #pragma unroll
      for (int kk = 0; kk < 16; ++kk) {
        float4 b4 = *(const float4*)(S + (kb + kk) * LDST + c0);
        #pragma unroll
        for (int i = 0; i < 4; ++i) {
          acc[i][0] += a[i][kk] * b4.x;
          acc[i][1] += a[i][kk] * b4.y;
          acc[i][2] += a[i][kk] * b4.z;
          acc[i][3] += a[i][kk] * b4.w;
        }
      }
    }
    #pragma unroll
    for (int i = 0; i < 4; ++i) {
      float4 o = {acc[i][0], acc[i][1], acc[i][2], acc[i][3]};
      *(float4*)(D + (r0 + i) * LDST + c0) = o;
      *(float4*)(Wm + j * 4096 + (r0 + i) * 64 + c0) = o;
    }
    __syncthreads();
    cur ^= 1;
  }
}

// ---------------- kernel C: states via checkpoints; emit PACKED bf16 hi/lo frags ----------------
// Chunk c covers t = 16c..16c+15 == packed tile16 index c exactly.
__global__ __launch_bounds__(64) void k_states(const float* __restrict__ Wm,
                                               const float* __restrict__ xh0,
                                               unsigned short* __restrict__ xpk) {
  __shared__ float sx[16 * LDST];   // 16 states x 64 comps, padded
  int c = blockIdx.x;       // 512 chunks of 16 steps
  int l = threadIdx.x;
  float v = xh0[l];
  int e = c << 4;
  for (int j = 4; j <= 12; ++j) {
    if ((e >> j) & 1) {
      const float* W = Wm + j * 4096;
      float n0 = 0.f, n1 = 0.f, n2 = 0.f, n3 = 0.f;
      #pragma unroll
      for (int k = 0; k < 64; k += 4) {
        n0 += W[l * 64 + k]     * __shfl(v, k, 64);
        n1 += W[l * 64 + k + 1] * __shfl(v, k + 1, 64);
        n2 += W[l * 64 + k + 2] * __shfl(v, k + 2, 64);
        n3 += W[l * 64 + k + 3] * __shfl(v, k + 3, 64);
      }
      v = (n0 + n1) + (n2 + n3);
    }
  }
  float m[64];
  #pragma unroll
  for (int k = 0; k < 64; ++k) m[k] = Wm[l * 64 + k];
  for (int i = 0; i < S_CHUNK; ++i) {
    float n0 = 0.f, n1 = 0.f, n2 = 0.f, n3 = 0.f;
    #pragma unroll
    for (int k = 0; k < 64; k += 4) {
      n0 += m[k]     * __shfl(v, k, 64);
      n1 += m[k + 1] * __shfl(v, k + 1, 64);
      n2 += m[k + 2] * __shfl(v, k + 2, 64);
      n3 += m[k + 3] * __shfl(v, k + 3, 64);
    }
    v = (n0 + n1) + (n2 + n3);
    sx[i * LDST + l] = v;            // state for t = 16c+i, component l
  }
  __syncthreads();

  // repack: 256 (lr, g) chunks over 64 threads x 4 iters; coalesced 16B stores
  #pragma unroll
  for (int it = 0; it < 4; ++it) {
    int idx = l + 64 * it;           // 0..255
    int lr = idx & 15, g = idx >> 4; // t-lane, k-chunk
    int k0 = (g & 7) * 8;
    float4 a = *(const float4*)(sx + lr * LDST + k0);
    float4 b = *(const float4*)(sx + lr * LDST + k0 + 4);
    float vv[8] = {a.x, a.y, a.z, a.w, b.x, b.y, b.z, b.w};
    ushort8 o;
    #pragma unroll
    for (int j = 0; j < 8; ++j) {
      unsigned short h = f2bf(vv[j]);
      o[j] = (g < 8) ? h : f2bf(vv[j] - bf2f(h));
    }
    *(ushort8*)(xpk + ((size_t)c * 256 + idx) * 8) = o;  // (c*16+g)*16+lr == c*256+idx
  }
}

// ---------------- kernel D: X_rec via bf16-split MFMA GEMM, NO LDS, fused err ----------------
// Operands pre-packed in fragment order -> each frag load is one coalesced
// 1 KiB dwordx4 per wave from L2. No staging, no barriers (round-6 lesson:
// 66 KiB LDS + barrier-serialized phases capped occupancy at 17% with all
// pipes <10%). acc 64 + frags 48 VGPRs; launch_bounds(256,3) targets 12 w/CU.
__global__ __launch_bounds__(256, 3) void k_xrec(const unsigned short* __restrict__ xpk,
                                                 const unsigned short* __restrict__ upk,
                                                 const float* __restrict__ Y,
                                                 float* __restrict__ Xrec,
                                                 double* __restrict__ acc_g) {
  __shared__ float red[512];

  int tid = threadIdx.x;
  int nt = blockIdx.x & 31, tt = blockIdx.x >> 5;
  int n0 = nt * 128, t0 = tt * 128;

  int l = tid & 63, wid = tid >> 6;
  int wr = wid >> 1, wc = wid & 1;
  int lr = l & 15, lg = l >> 4;

  int xt = (t0 >> 4) + wr * 4;   // +m  -> X tile16
  int un = (n0 >> 4) + wc * 4;   // +nf -> U tile16

  f32x4 acc[4][4];
  #pragma unroll
  for (int m = 0; m < 4; ++m)
    #pragma unroll
    for (int nf = 0; nf < 4; ++nf) acc[m][nf] = (f32x4){0.f, 0.f, 0.f, 0.f};

  bf16x8 af[4], bfr[4], bf2r[4];

  // group A: X hi k0 (gb=0) x { U hi k0 (gb=0), U lo k0 (gb=8) }
  #pragma unroll
  for (int m = 0; m < 4; ++m)  af[m]   = ldfrag(xpk, xt + m, 0, lg, lr);
  #pragma unroll
  for (int nf = 0; nf < 4; ++nf) bfr[nf]  = ldfrag(upk, un + nf, 0, lg, lr);
  #pragma unroll
  for (int nf = 0; nf < 4; ++nf) bf2r[nf] = ldfrag(upk, un + nf, 8, lg, lr);
  #pragma unroll
  for (int m = 0; m < 4; ++m)
    #pragma unroll
    for (int nf = 0; nf < 4; ++nf)
      acc[m][nf] = __builtin_amdgcn_mfma_f32_16x16x32_bf16(bfr[nf], af[m], acc[m][nf], 0, 0, 0);
  #pragma unroll
  for (int m = 0; m < 4; ++m)
    #pragma unroll
    for (int nf = 0; nf < 4; ++nf)
      acc[m][nf] = __builtin_amdgcn_mfma_f32_16x16x32_bf16(bf2r[nf], af[m], acc[m][nf], 0, 0, 0);

  // group B: X hi k32 (gb=4) x { U hi k32 (gb=4), U lo k32 (gb=12) }
  #pragma unroll
  for (int m = 0; m < 4; ++m)  af[m]   = ldfrag(xpk, xt + m, 4, lg, lr);
  #pragma unroll
  for (int nf = 0; nf < 4; ++nf) bfr[nf]  = ldfrag(upk, un + nf, 4, lg, lr);
  #pragma unroll
  for (int nf = 0; nf < 4; ++nf) bf2r[nf] = ldfrag(upk, un + nf, 12, lg, lr);
  #pragma unroll
  for (int m = 0; m < 4; ++m)
    #pragma unroll
    for (int nf = 0; nf < 4; ++nf)
      acc[m][nf] = __builtin_amdgcn_mfma_f32_16x16x32_bf16(bfr[nf], af[m], acc[m][nf], 0, 0, 0);
  #pragma unroll
  for (int m = 0; m < 4; ++m)
    #pragma unroll
    for (int nf = 0; nf < 4; ++nf)
      acc[m][nf] = __builtin_amdgcn_mfma_f32_16x16x32_bf16(bf2r[nf], af[m], acc[m][nf], 0, 0, 0);

  // group C: X lo k0 (gb=8) x U hi k0 (gb=0)
  #pragma unroll
  for (int m = 0; m < 4; ++m)  af[m]  = ldfrag(xpk, xt + m, 8, lg, lr);
  #pragma unroll
  for (int nf = 0; nf < 4; ++nf) bfr[nf] = ldfrag(upk, un + nf, 0, lg, lr);
  #pragma unroll
  for (int m = 0; m < 4; ++m)
    #pragma unroll
    for (int nf = 0; nf < 4; ++nf)
      acc[m][nf] = __builtin_amdgcn_mfma_f32_16x16x32_bf16(bfr[nf], af[m], acc[m][nf], 0, 0, 0);

  // group D: X lo k32 (gb=12) x U hi k32 (gb=4)
  #pragma unroll
  for (int m = 0; m < 4; ++m)  af[m]  = ldfrag(xpk, xt + m, 12, lg, lr);
  #pragma unroll
  for (int nf = 0; nf < 4; ++nf) bfr[nf] = ldfrag(upk, un + nf, 4, lg, lr);
  #pragma unroll
  for (int m = 0; m < 4; ++m)
    #pragma unroll
    for (int nf = 0; nf < 4; ++nf)
      acc[m][nf] = __builtin_amdgcn_mfma_f32_16x16x32_bf16(bfr[nf], af[m], acc[m][nf], 0, 0, 0);

  // epilogue: lane holds 4 consecutive n (regs) at fixed t -> float4 I/O
  float sd = 0.f, sy = 0.f;
  #pragma unroll
  for (int m = 0; m < 4; ++m) {
    #pragma unroll
    for (int nf = 0; nf < 4; ++nf) {
      int t = t0 + wr * 64 + m * 16 + lr;
      int n = n0 + wc * 64 + nf * 16 + lg * 4;
      size_t idx = (size_t)t * N_DIM + n;
      float4 y = *(const float4*)(Y + idx);
      f32x4 v = acc[m][nf];
      float d;
      d = y.x - v[0]; sd += d * d; sy += y.x * y.x;
      d = y.y - v[1]; sd += d * d; sy += y.y * y.y;
      d = y.z - v[2]; sd += d * d; sy += y.z * y.z;
      d = y.w - v[3]; sd += d * d; sy += y.w * y.w;
      __builtin_nontemporal_store(v, (f32x4*)(Xrec + idx));
    }
  }

  red[tid] = sd; red[256 + tid] = sy;
  __syncthreads();
  for (int s2 = 128; s2 > 0; s2 >>= 1) {
    if (tid < s2) { red[tid] += red[tid + s2]; red[256 + tid] += red[256 + tid + s2]; }
    __syncthreads();
  }
  if (tid == 0) {
    atomicAdd(acc_g,     (double)red[0]);
    atomicAdd(acc_g + 1, (double)red[256]);
  }
}

// ---------------- kernel E: finalize err ----------------
__global__ void k_err(const double* __restrict__ acc, float* __restrict__ out_tail) {
  out_tail[0] = (float)sqrt(acc[0] / acc[1]);
}

extern "C" void kernel_launch(void* const* d_in, const int* in_sizes, int n_in,
                              void* d_out, int out_size, void* d_ws, size_t ws_size,
                              hipStream_t stream) {
  const float* X_train = (const float*)d_in[1];
  const float* Y       = (const float*)d_in[2];
  const float* temp    = (const float*)d_in[3];
  const float* phi     = (const float*)d_in[4];
  const float* A_tilde = (const float*)d_in[5];
  const float* U       = (const float*)d_in[6];
  const float* logits  = (const float*)d_in[7];
  float* out = (float*)d_out;
  float* out_tail = out + (size_t)T_DIM * N_DIM;

  // workspace layout (bytes)
  char* w = (char*)d_ws;
  double* acc          = (double*)w;                     // @0, 16 B
  float* Wm            = (float*)(w + 64);               // 13*16384 B -> ends 213056
  float* xh0           = (float*)(w + 213056);           // 256 B
  float* part          = (float*)(w + 213312);           // 16384 B -> ends 229696
  unsigned short* upk  = (unsigned short*)(w + 262144);  // 1 MiB packed U frags
  unsigned short* xpk  = (unsigned short*)(w + 1310720); // 2 MiB packed X frags -> ends 3407872

  k_xh0_part<<<64, 64, 0, stream>>>(U, X_train, part, acc);
  k_usplit<<<(N_DIM / 16), 256, 0, stream>>>(U, upk);
  k_prep<<<1, 256, 0, stream>>>(A_tilde, phi, logits, temp, part, Wm, xh0, out_tail);
  k_states<<<N_CHUNK, 64, 0, stream>>>(Wm, xh0, xpk);
  k_xrec<<<2048, 256, 0, stream>>>(xpk, upk, Y, out, acc);
  k_err<<<1, 1, 0, stream>>>(acc, out_tail);
}